// Round 1
// baseline (208.099 us; speedup 1.0000x reference)
//
#include <hip/hip_runtime.h>
#include <math.h>

// Problem constants: N=1024, C=128, H=4, HD=32, HID=64
//
// Algebraic restructuring:
//   u[n,m]   = pos[n,:] @ W1[:,m]                       (hid[i,j,m] = (u[i,m]+b1[m]) - u[j,m])
//   A[n,h,m] = sum_d q[n,h*32+d] * W2[m, h*32+d]        (geom_attn = sum_m relu(hid)*A + c)
//   c[n,h]   = sum_d q[n,h*32+d] * b2[h*32+d]
//   score[h,i,j] = (q_i . k_j)/sqrt(32) + sum_m relu(hid)*A[i,h,m] + c[i,h] - dist(i,j)
//   softmax without max-subtraction (scores bounded ~[-15, +1] -> exp safe in fp32)

static __device__ __forceinline__ float dot4(float4 a, float4 b) {
  return a.x*b.x + a.y*b.y + a.z*b.z + a.w*b.w;
}

// ---------------- K1: precompute q,k,v,u,A,c ----------------
__global__ __launch_bounds__(256) void k_pre(
    const float* __restrict__ x, const float* __restrict__ y, const float* __restrict__ pos,
    const float* __restrict__ Wq, const float* __restrict__ bq,
    const float* __restrict__ Wk, const float* __restrict__ bk,
    const float* __restrict__ Wv, const float* __restrict__ bv,
    const float* __restrict__ W1,
    const float* __restrict__ W2, const float* __restrict__ b2,
    float* __restrict__ q, float* __restrict__ k, float* __restrict__ v,
    float* __restrict__ u, float* __restrict__ A, float* __restrict__ cvec)
{
  __shared__ float xs[512], ys[512], qs[512], ps[12];
  const int t  = threadIdx.x;
  const int n0 = blockIdx.x * 4;

  for (int idx = t; idx < 512; idx += 256) {
    xs[idx] = x[n0*128 + idx];
    ys[idx] = y[n0*128 + idx];
  }
  if (t < 12) ps[t] = pos[n0*3 + t];
  __syncthreads();

  // phase A: q,k,v for 4 rows (thread = (col c, group g); rows g and g+2)
  const int c = t & 127;
  const int g = t >> 7;
  const int r0 = g, r1 = g + 2;
  float qa0=0.f, ka0=0.f, va0=0.f, qa1=0.f, ka1=0.f, va1=0.f;
  for (int d = 0; d < 128; ++d) {
    const float wq_ = Wq[d*128+c], wk_ = Wk[d*128+c], wv_ = Wv[d*128+c];
    const float x0 = xs[r0*128+d], y0 = ys[r0*128+d];
    const float x1 = xs[r1*128+d], y1 = ys[r1*128+d];
    qa0 = fmaf(x0, wq_, qa0); ka0 = fmaf(y0, wk_, ka0); va0 = fmaf(y0, wv_, va0);
    qa1 = fmaf(x1, wq_, qa1); ka1 = fmaf(y1, wk_, ka1); va1 = fmaf(y1, wv_, va1);
  }
  qa0 += bq[c]; ka0 += bk[c]; va0 += bv[c];
  qa1 += bq[c]; ka1 += bk[c]; va1 += bv[c];
  q[(n0+r0)*128+c] = qa0; k[(n0+r0)*128+c] = ka0; v[(n0+r0)*128+c] = va0;
  q[(n0+r1)*128+c] = qa1; k[(n0+r1)*128+c] = ka1; v[(n0+r1)*128+c] = va1;
  qs[r0*128+c] = qa0; qs[r1*128+c] = qa1;
  __syncthreads();

  // phase B: u, A, c (thread = (row ni, feature m))
  const int m  = t & 63;
  const int ni = t >> 6;
  const int n  = n0 + ni;
  float ua = 0.f;
  for (int tt = 0; tt < 3; ++tt) ua = fmaf(ps[ni*3+tt], W1[tt*64+m], ua);
  u[n*64+m] = ua;
  #pragma unroll
  for (int h = 0; h < 4; ++h) {
    float aa = 0.f;
    #pragma unroll
    for (int d = 0; d < 32; ++d)
      aa = fmaf(qs[ni*128 + h*32 + d], W2[m*128 + h*32 + d], aa);
    A[(n*4+h)*64 + m] = aa;
  }
  if (m < 4) {
    const int h = m;
    float ca = 0.f;
    for (int d = 0; d < 32; ++d) ca = fmaf(qs[ni*128 + h*32 + d], b2[h*32 + d], ca);
    cvec[n*4+h] = ca;
  }
}

// ---------------- K2: fused scores + softmax + PV ----------------
// grid 512 blocks x 512 threads. Block: 2 i-rows; wave w: r=w&1 (row), quarter=w>>1.
// Per tile (64 j): lane scores its one j, writes p to wave-private LDS E-tile;
// then lanes switch to d-parallel layout (c4 = lane&31, rep = lane>>5 splits j)
// for the PV accumulation -> accumulator is just one float4 per lane.
__global__ __launch_bounds__(512, 4) void k_attn(
    const float* __restrict__ pos,
    const float* __restrict__ q, const float* __restrict__ k, const float* __restrict__ v,
    const float* __restrict__ u, const float* __restrict__ A, const float* __restrict__ cvec,
    const float* __restrict__ b1,
    float* __restrict__ out)
{
  __shared__ float posL[3072];
  __shared__ float upL[128];      // (u + b1) for the 2 i-rows
  __shared__ float qL[256];
  __shared__ float aL[512];
  __shared__ float cL[8];
  __shared__ float eL[8*280];     // per-wave E tile, row stride 68 (2-way banks only)
  __shared__ float redAcc[2048];  // [r][quarter][rep][c4] as float4
  __shared__ float redL[32];      // [r][quarter][h]

  const int t  = threadIdx.x;
  const int i0 = blockIdx.x * 2;

  {
    const float4* p4 = (const float4*)pos;
    float4* pl4 = (float4*)posL;
    for (int idx = t; idx < 768; idx += 512) pl4[idx] = p4[idx];
  }
  if (t < 128) upL[t] = u[i0*64 + t] + b1[t & 63];
  if (t >= 128 && t < 384) qL[t-128] = q[i0*128 + (t-128)];
  aL[t] = A[i0*256 + t];
  if (t < 8) cL[t] = cvec[i0*4 + t];
  __syncthreads();

  const int w = t >> 6;
  const int lane = t & 63;
  const int r = w & 1;
  const int quarter = w >> 1;
  const int i = i0 + r;
  const int c4 = lane & 31;
  const int rep = lane >> 5;
  const int hh = c4 >> 3;

  const float pix = posL[i*3], piy = posL[i*3+1], piz = posL[i*3+2];

  const float4* u4 = (const float4*)u;
  const float4* k4 = (const float4*)k;
  const float4* v4 = (const float4*)v;
  const float4* uprow = (const float4*)&upL[r*64];
  const float4* arow  = (const float4*)&aL[r*256];
  const float4* qrow  = (const float4*)&qL[r*128];
  const float ci0 = cL[r*4+0], ci1 = cL[r*4+1], ci2 = cL[r*4+2], ci3 = cL[r*4+3];

  float4 accv = make_float4(0.f, 0.f, 0.f, 0.f);
  float l0=0.f, l1=0.f, l2=0.f, l3=0.f;
  const float RS = 0.17677669529663687f;  // 1/sqrt(32)

  for (int tt = 0; tt < 4; ++tt) {
    const int jt = tt*4 + quarter;
    const int j  = jt*64 + lane;

    // dist
    const float dx = pix - posL[j*3], dy = piy - posL[j*3+1], dz = piz - posL[j*3+2];
    const float dist = sqrtf(dx*dx + dy*dy + dz*dz);

    // geom: sum_m relu((u_i+b1) - u_j) * A[i,h,m] + c
    float g0 = ci0, g1 = ci1, g2 = ci2, g3 = ci3;
    #pragma unroll
    for (int mb = 0; mb < 16; ++mb) {
      const float4 uj = u4[j*16 + mb];
      const float4 ub = uprow[mb];
      const float h0 = fmaxf(ub.x - uj.x, 0.f);
      const float h1 = fmaxf(ub.y - uj.y, 0.f);
      const float h2 = fmaxf(ub.z - uj.z, 0.f);
      const float h3 = fmaxf(ub.w - uj.w, 0.f);
      const float4 a0 = arow[mb], a1 = arow[16+mb], a2 = arow[32+mb], a3 = arow[48+mb];
      g0 += h0*a0.x + h1*a0.y + h2*a0.z + h3*a0.w;
      g1 += h0*a1.x + h1*a1.y + h2*a1.z + h3*a1.w;
      g2 += h0*a2.x + h1*a2.y + h2*a2.z + h3*a2.w;
      g3 += h0*a3.x + h1*a3.y + h2*a3.z + h3*a3.w;
    }

    // qk
    float s0=0.f, s1=0.f, s2=0.f, s3=0.f;
    #pragma unroll
    for (int cb = 0; cb < 8; ++cb) {
      s0 += dot4(k4[j*32+cb],    qrow[cb]);
      s1 += dot4(k4[j*32+8+cb],  qrow[8+cb]);
      s2 += dot4(k4[j*32+16+cb], qrow[16+cb]);
      s3 += dot4(k4[j*32+24+cb], qrow[24+cb]);
    }

    const float p0 = __expf(fmaf(s0, RS, g0) - dist);
    const float p1 = __expf(fmaf(s1, RS, g1) - dist);
    const float p2 = __expf(fmaf(s2, RS, g2) - dist);
    const float p3 = __expf(fmaf(s3, RS, g3) - dist);
    l0 += p0; l1 += p1; l2 += p2; l3 += p3;

    float* ew = &eL[w*280];
    ew[lane] = p0; ew[68+lane] = p1; ew[136+lane] = p2; ew[204+lane] = p3;
    __syncthreads();

    // PV, d-parallel: lane owns c-quad c4 (head hh), rep splits the 64 j's
    const float* er = &eL[w*280 + hh*68 + rep*32];
    const float4* vb = &v4[(jt*64 + rep*32)*32 + c4];
    #pragma unroll
    for (int jj = 0; jj < 32; ++jj) {
      const float e = er[jj];
      const float4 vv = vb[jj*32];
      accv.x = fmaf(e, vv.x, accv.x);
      accv.y = fmaf(e, vv.y, accv.y);
      accv.z = fmaf(e, vv.z, accv.z);
      accv.w = fmaf(e, vv.w, accv.w);
    }
    __syncthreads();
  }

  // partial out per (r, quarter, rep, c4)
  ((float4*)redAcc)[((r*4 + quarter)*2 + rep)*32 + c4] = accv;

  // row-sum l: butterfly within wave, then one slot per (r, quarter)
  #pragma unroll
  for (int mm = 1; mm < 64; mm <<= 1) {
    l0 += __shfl_xor(l0, mm);
    l1 += __shfl_xor(l1, mm);
    l2 += __shfl_xor(l2, mm);
    l3 += __shfl_xor(l3, mm);
  }
  if (lane == 0) {
    float* rl = &redL[(r*4+quarter)*4];
    rl[0]=l0; rl[1]=l1; rl[2]=l2; rl[3]=l3;
  }
  __syncthreads();

  if (t < 256) {
    const int rr = t >> 7, cc = t & 127;
    const int hq = cc >> 5;
    float s = 0.f;
    float L = 0.f;
    #pragma unroll
    for (int qq = 0; qq < 4; ++qq) {
      s += redAcc[(((rr*4+qq)*2+0)*32 + (cc>>2))*4 + (cc&3)];
      s += redAcc[(((rr*4+qq)*2+1)*32 + (cc>>2))*4 + (cc&3)];
      L += redL[(rr*4+qq)*4 + hq];
    }
    out[(i0+rr)*128 + cc] = s / L;
  }
}

extern "C" void kernel_launch(void* const* d_in, const int* in_sizes, int n_in,
                              void* d_out, int out_size, void* d_ws, size_t ws_size,
                              hipStream_t stream) {
  const float* x   = (const float*)d_in[0];
  const float* y   = (const float*)d_in[1];
  const float* pos = (const float*)d_in[2];
  const float* Wq  = (const float*)d_in[3];
  const float* bq  = (const float*)d_in[4];
  const float* Wk  = (const float*)d_in[5];
  const float* bk  = (const float*)d_in[6];
  const float* Wv  = (const float*)d_in[7];
  const float* bv  = (const float*)d_in[8];
  const float* W1  = (const float*)d_in[9];
  const float* b1  = (const float*)d_in[10];
  const float* W2  = (const float*)d_in[11];
  const float* b2  = (const float*)d_in[12];

  float* ws = (float*)d_ws;
  float* q  = ws;            // 1024*128
  float* k  = ws + 131072;   // 1024*128
  float* v  = ws + 262144;   // 1024*128
  float* u  = ws + 393216;   // 1024*64
  float* A  = ws + 458752;   // 1024*4*64
  float* cv = ws + 720896;   // 1024*4
  float* out = (float*)d_out;

  k_pre<<<dim3(256), dim3(256), 0, stream>>>(x, y, pos, Wq, bq, Wk, bk, Wv, bv,
                                             W1, W2, b2, q, k, v, u, A, cv);
  k_attn<<<dim3(512), dim3(512), 0, stream>>>(pos, q, k, v, u, A, cv, b1, out);
}

// Round 2
// 203.202 us; speedup vs baseline: 1.0241x; 1.0241x over previous
//
#include <hip/hip_runtime.h>
#include <math.h>

// Problem constants: N=1024, C=128, H=4, HD=32, HID=64
//
//   u[n,m]   = pos[n,:] @ W1[:,m]       (hid[i,j,m] = (u[i,m]+b1[m]) - u[j,m])
//   A[n,h,m] = sum_d q[n,h*32+d] * W2[m, h*32+d]
//   c[n,h]   = sum_d q[n,h*32+d] * b2[h*32+d]
//   score[h,i,j] = (q_i.k_j)/sqrt(32) + sum_m relu(hid)*A[i,h,m] + c[i,h] - dist(i,j)
//   softmax without max-subtraction (scores bounded ~[-15,+1] -> exp safe in fp32)

static __device__ __forceinline__ float dot4(float4 a, float4 b) {
  return a.x*b.x + a.y*b.y + a.z*b.z + a.w*b.w;
}

// ---------------- K1: precompute q,k,v,u,A,c,pos4 ----------------
// 512 blocks x 384 threads; block = 2 rows. Thread = (col, matrix-id).
__global__ __launch_bounds__(384) void k_pre(
    const float* __restrict__ x, const float* __restrict__ y, const float* __restrict__ pos,
    const float* __restrict__ Wq, const float* __restrict__ bq,
    const float* __restrict__ Wk, const float* __restrict__ bk,
    const float* __restrict__ Wv, const float* __restrict__ bv,
    const float* __restrict__ W1,
    const float* __restrict__ W2, const float* __restrict__ b2,
    float* __restrict__ q, float* __restrict__ k, float* __restrict__ v,
    float* __restrict__ u, float* __restrict__ A, float* __restrict__ cvec,
    float* __restrict__ pos4w)
{
  __shared__ float xs[256], ys[256], qs[256];
  const int t  = threadIdx.x;
  const int n0 = blockIdx.x * 2;

  if (t < 256) { xs[t] = x[n0*128 + t]; ys[t] = y[n0*128 + t]; }
  __syncthreads();

  // phase A: q,k,v. thread = (c = t&127, mat = t>>7); 2 rows each.
  {
    const int c   = t & 127;
    const int mat = t >> 7;  // wave-uniform
    const float* W    = (mat == 0) ? Wq : (mat == 1 ? Wk : Wv);
    const float* src  = (mat == 0) ? xs : ys;
    const float* bias = (mat == 0) ? bq : (mat == 1 ? bk : bv);
    float a0 = 0.f, a1 = 0.f;
    #pragma unroll 8
    for (int d = 0; d < 128; ++d) {
      const float w_ = W[d*128 + c];
      a0 = fmaf(src[d],       w_, a0);
      a1 = fmaf(src[128 + d], w_, a1);
    }
    a0 += bias[c]; a1 += bias[c];
    float* dst = (mat == 0) ? q : (mat == 1 ? k : v);
    dst[n0*128 + c] = a0; dst[(n0+1)*128 + c] = a1;
    if (mat == 0) { qs[c] = a0; qs[128 + c] = a1; }
  }
  __syncthreads();

  // phase B: u, A, c, pos4
  if (t < 128) {
    const int m = t & 63, ni = t >> 6;
    float ua = 0.f;
    #pragma unroll
    for (int tt = 0; tt < 3; ++tt) ua = fmaf(pos[(n0+ni)*3 + tt], W1[tt*64 + m], ua);
    u[(n0+ni)*64 + m] = ua;
  }
  if (t < 256) {
    const int m = t & 63, hp = (t >> 6) & 1, ni = t >> 7;
    #pragma unroll
    for (int hi = 0; hi < 2; ++hi) {
      const int h = hp*2 + hi;
      float aa = 0.f;
      #pragma unroll
      for (int d = 0; d < 32; ++d)
        aa = fmaf(qs[ni*128 + h*32 + d], W2[m*128 + h*32 + d], aa);
      A[((n0+ni)*4 + h)*64 + m] = aa;
    }
  }
  if (t < 8) {
    const int ni = t >> 2, h = t & 3;
    float ca = 0.f;
    #pragma unroll
    for (int d = 0; d < 32; ++d) ca = fmaf(qs[ni*128 + h*32 + d], b2[h*32 + d], ca);
    cvec[(n0+ni)*4 + h] = ca;
    // pos4 (padded): reuse same 8 threads, (r = ni, comp = h) won't cover comp=3 pad... do explicit
  }
  if (t < 8) {
    const int r = t >> 2, cm = t & 3;
    pos4w[(n0+r)*4 + cm] = (cm < 3) ? pos[(n0+r)*3 + cm] : 0.f;
  }
}

// ---------------- K2: fused scores + softmax + PV ----------------
// 512 blocks x 512 threads. Block: 2 i-rows; wave w: r=w&1, quarter=w>>1.
// NO block barriers in the tile loop: the E exchange is wave-private LDS
// (DS ops are in-order within a wave; wave_barrier stops compiler motion).
__global__ __launch_bounds__(512, 4) void k_attn(
    const float4* __restrict__ pos4,
    const float* __restrict__ q, const float* __restrict__ k, const float* __restrict__ v,
    const float* __restrict__ u, const float* __restrict__ A, const float* __restrict__ cvec,
    const float* __restrict__ b1,
    float* __restrict__ out)
{
  __shared__ float upL[128];      // (u + b1) for the 2 i-rows
  __shared__ float qL[256];
  __shared__ float aL[512];
  __shared__ float cL[8];
  __shared__ __align__(16) float eL[8*280];     // per-wave E tile, row stride 68
  __shared__ float redAcc[2048];  // [r][quarter][rep][c4] as float4
  __shared__ float redL[32];      // [r][quarter][h]

  const int t  = threadIdx.x;
  const int i0 = blockIdx.x * 2;

  if (t < 128) upL[t] = u[i0*64 + t] + b1[t & 63];
  if (t >= 128 && t < 384) qL[t-128] = q[i0*128 + (t-128)];
  aL[t] = A[i0*256 + t];
  if (t < 8) cL[t] = cvec[i0*4 + t];
  __syncthreads();

  const int w = t >> 6;
  const int lane = t & 63;
  const int r = w & 1;
  const int quarter = w >> 1;
  const int i = i0 + r;
  const int c4 = lane & 31;
  const int rep = lane >> 5;
  const int hh = c4 >> 3;

  const float4 pi = pos4[i];

  const float4* u4 = (const float4*)u;
  const float4* k4 = (const float4*)k;
  const float4* v4 = (const float4*)v;
  const float4* uprow = (const float4*)&upL[r*64];
  const float4* arow  = (const float4*)&aL[r*256];
  const float4* qrow  = (const float4*)&qL[r*128];
  const float ci0 = cL[r*4+0], ci1 = cL[r*4+1], ci2 = cL[r*4+2], ci3 = cL[r*4+3];

  float4 accv = make_float4(0.f, 0.f, 0.f, 0.f);
  float l0=0.f, l1=0.f, l2=0.f, l3=0.f;
  const float RS = 0.17677669529663687f;  // 1/sqrt(32)

  for (int tt = 0; tt < 4; ++tt) {
    const int jt = tt*4 + quarter;
    const int j  = jt*64 + lane;

    // dist
    const float4 pj = pos4[j];
    const float dx = pi.x - pj.x, dy = pi.y - pj.y, dz = pi.z - pj.z;
    const float dist = sqrtf(dx*dx + dy*dy + dz*dz);

    // geom: sum_m relu((u_i+b1) - u_j) * A[i,h,m] + c
    float g0 = ci0, g1 = ci1, g2 = ci2, g3 = ci3;
    #pragma unroll
    for (int mb = 0; mb < 16; ++mb) {
      const float4 uj = u4[j*16 + mb];
      const float4 ub = uprow[mb];
      const float h0 = fmaxf(ub.x - uj.x, 0.f);
      const float h1 = fmaxf(ub.y - uj.y, 0.f);
      const float h2 = fmaxf(ub.z - uj.z, 0.f);
      const float h3 = fmaxf(ub.w - uj.w, 0.f);
      const float4 a0 = arow[mb], a1 = arow[16+mb], a2 = arow[32+mb], a3 = arow[48+mb];
      g0 += h0*a0.x + h1*a0.y + h2*a0.z + h3*a0.w;
      g1 += h0*a1.x + h1*a1.y + h2*a1.z + h3*a1.w;
      g2 += h0*a2.x + h1*a2.y + h2*a2.z + h3*a2.w;
      g3 += h0*a3.x + h1*a3.y + h2*a3.z + h3*a3.w;
    }

    // qk
    float s0=0.f, s1=0.f, s2=0.f, s3=0.f;
    #pragma unroll
    for (int cb = 0; cb < 8; ++cb) {
      s0 += dot4(k4[j*32+cb],    qrow[cb]);
      s1 += dot4(k4[j*32+8+cb],  qrow[8+cb]);
      s2 += dot4(k4[j*32+16+cb], qrow[16+cb]);
      s3 += dot4(k4[j*32+24+cb], qrow[24+cb]);
    }

    const float p0 = __expf(fmaf(s0, RS, g0) - dist);
    const float p1 = __expf(fmaf(s1, RS, g1) - dist);
    const float p2 = __expf(fmaf(s2, RS, g2) - dist);
    const float p3 = __expf(fmaf(s3, RS, g3) - dist);
    l0 += p0; l1 += p1; l2 += p2; l3 += p3;

    // wave-private exchange (no block barrier needed)
    float* ew = &eL[w*280];
    ew[lane] = p0; ew[68+lane] = p1; ew[136+lane] = p2; ew[204+lane] = p3;
    __builtin_amdgcn_wave_barrier();

    // PV, d-parallel: lane owns c-quad c4 (head hh), rep splits the 64 j's
    const float4* er4 = (const float4*)&eL[w*280 + hh*68 + rep*32];
    const float4* vb  = &v4[(jt*64 + rep*32)*32 + c4];
    #pragma unroll
    for (int jj4 = 0; jj4 < 8; ++jj4) {
      const float4 e4 = er4[jj4];
      const float4 v0 = vb[(jj4*4+0)*32];
      const float4 v1 = vb[(jj4*4+1)*32];
      const float4 v2 = vb[(jj4*4+2)*32];
      const float4 v3 = vb[(jj4*4+3)*32];
      accv.x = fmaf(e4.x, v0.x, accv.x); accv.y = fmaf(e4.x, v0.y, accv.y);
      accv.z = fmaf(e4.x, v0.z, accv.z); accv.w = fmaf(e4.x, v0.w, accv.w);
      accv.x = fmaf(e4.y, v1.x, accv.x); accv.y = fmaf(e4.y, v1.y, accv.y);
      accv.z = fmaf(e4.y, v1.z, accv.z); accv.w = fmaf(e4.y, v1.w, accv.w);
      accv.x = fmaf(e4.z, v2.x, accv.x); accv.y = fmaf(e4.z, v2.y, accv.y);
      accv.z = fmaf(e4.z, v2.z, accv.z); accv.w = fmaf(e4.z, v2.w, accv.w);
      accv.x = fmaf(e4.w, v3.x, accv.x); accv.y = fmaf(e4.w, v3.y, accv.y);
      accv.z = fmaf(e4.w, v3.z, accv.z); accv.w = fmaf(e4.w, v3.w, accv.w);
    }
    __builtin_amdgcn_wave_barrier();
  }

  // partial out per (r, quarter, rep, c4)
  ((float4*)redAcc)[((r*4 + quarter)*2 + rep)*32 + c4] = accv;

  // row-sum l: butterfly within wave, then one slot per (r, quarter)
  #pragma unroll
  for (int mm = 1; mm < 64; mm <<= 1) {
    l0 += __shfl_xor(l0, mm);
    l1 += __shfl_xor(l1, mm);
    l2 += __shfl_xor(l2, mm);
    l3 += __shfl_xor(l3, mm);
  }
  if (lane == 0) {
    float* rl = &redL[(r*4+quarter)*4];
    rl[0]=l0; rl[1]=l1; rl[2]=l2; rl[3]=l3;
  }
  __syncthreads();

  if (t < 256) {
    const int rr = t >> 7, cc = t & 127;
    const int hq = cc >> 5;
    float s = 0.f;
    float L = 0.f;
    #pragma unroll
    for (int qq = 0; qq < 4; ++qq) {
      s += redAcc[(((rr*4+qq)*2+0)*32 + (cc>>2))*4 + (cc&3)];
      s += redAcc[(((rr*4+qq)*2+1)*32 + (cc>>2))*4 + (cc&3)];
      L += redL[(rr*4+qq)*4 + hq];
    }
    out[(i0+rr)*128 + cc] = s / L;
  }
}

extern "C" void kernel_launch(void* const* d_in, const int* in_sizes, int n_in,
                              void* d_out, int out_size, void* d_ws, size_t ws_size,
                              hipStream_t stream) {
  const float* x   = (const float*)d_in[0];
  const float* y   = (const float*)d_in[1];
  const float* pos = (const float*)d_in[2];
  const float* Wq  = (const float*)d_in[3];
  const float* bq  = (const float*)d_in[4];
  const float* Wk  = (const float*)d_in[5];
  const float* bk  = (const float*)d_in[6];
  const float* Wv  = (const float*)d_in[7];
  const float* bv  = (const float*)d_in[8];
  const float* W1  = (const float*)d_in[9];
  const float* b1  = (const float*)d_in[10];
  const float* W2  = (const float*)d_in[11];
  const float* b2  = (const float*)d_in[12];

  float* ws = (float*)d_ws;
  float* q    = ws;            // 1024*128
  float* k    = ws + 131072;   // 1024*128
  float* v    = ws + 262144;   // 1024*128
  float* u    = ws + 393216;   // 1024*64
  float* A    = ws + 458752;   // 1024*4*64
  float* cv   = ws + 720896;   // 1024*4
  float* pos4 = ws + 724992;   // 1024*4 (padded pos)
  float* out = (float*)d_out;

  k_pre<<<dim3(512), dim3(384), 0, stream>>>(x, y, pos, Wq, bq, Wk, bk, Wv, bv,
                                             W1, W2, b2, q, k, v, u, A, cv, pos4);
  k_attn<<<dim3(512), dim3(512), 0, stream>>>((const float4*)pos4, q, k, v, u, A, cv, b1, out);
}